// Round 7
// baseline (233.126 us; speedup 1.0000x reference)
//
#include <hip/hip_runtime.h>
#include <hip/hip_cooperative_groups.h>
#include <stdint.h>

namespace cg = cooperative_groups;

#define W 768
#define NPROB (768*768)
#define NB 8
#define NBINS 2048
#define CAP 4096
#define TOPK 2048
#define SCORE_THR 0.6f
#define NBLOCKS 256
#define NTHREADS 256
#define SUBS 32                   // blocks per batch (hist/compact/rank)
#define PER4 (NPROB/4/SUBS)       // 4608 float4 per sub-block

// ws layout (bytes). cellmap needs NO init: stale/poison values (0xAAAA/0xFFFF)
// are >2047 so the `rank < myrank` test ignores them; cells written this call
// are reset in the cleanup tail, so every replay sees the same behavior.
#define MAP_OFF    0
#define MAP_BYTES  (NB*NPROB*2)                 // 9,437,184
#define HIST_OFF   (MAP_OFF + MAP_BYTES)
#define HIST_BYTES (NB*NBINS*4)                 // 65,536
#define META_OFF   (HIST_OFF + HIST_BYTES)
#define PFX_OFF    (META_OFF + 256)
#define PFX_BYTES  (NB*(NBINS+1)*4)
#define CUR_OFF    (PFX_OFF + PFX_BYTES)
#define CUR_BYTES  (NB*NBINS*4)
#define CAND_OFF   (CUR_OFF + CUR_BYTES)
#define CAND_BYTES (NB*CAP*8)
#define SKEY_OFF   (CAND_OFF + CAND_BYTES)
#define SKEY_BYTES (NB*TOPK*8)
#define WS_TOTAL   (SKEY_OFF + SKEY_BYTES)

struct Meta { unsigned bstar; unsigned cnt; unsigned pad0; unsigned pad1; };

// bin over float bits: valid scores are in [0.6,1.0) -> one binade, bits monotone
__device__ __forceinline__ unsigned score_bin(unsigned fb) {
    return (fb >> 13) & 0x7FFu;
}

union SMem {
    unsigned lh[NBINS];                                                        // 8 KB
    struct { unsigned h[NBINS]; unsigned pfx[NBINS+1]; unsigned csum[256]; unsigned sb; } sel;
    struct { unsigned long long k[CAP]; unsigned pfx[NBINS+1]; } rk;           // 40.2 KB
    struct { unsigned char state[TOPK]; int changed; } fx;                     // 2 KB
};

__global__ __launch_bounds__(NTHREADS) void fused_kernel(
    const float* __restrict__ probs, const float* __restrict__ dev4,
    float* __restrict__ out, unsigned short* __restrict__ cellmap,
    unsigned* __restrict__ hist, Meta* __restrict__ meta,
    unsigned* __restrict__ binpfx, unsigned* __restrict__ cursor,
    unsigned long long* __restrict__ cand, unsigned long long* __restrict__ skey)
{
    cg::grid_group grid = cg::this_grid();
    __shared__ SMem sm;
    const int bid = blockIdx.x, tid = threadIdx.x;
    const int hb = bid / SUBS;        // batch for hist/compact/rank phases
    const int hs = bid % SUBS;        // sub-block within batch

    // ---- P0: zero global hist (first 64 blocks) + local LDS hist ----
    { int g = bid * NTHREADS + tid; if (g < NB * NBINS) hist[g] = 0; }
    for (int i = tid; i < NBINS; i += NTHREADS) sm.lh[i] = 0;
    __syncthreads();
    {
        const float4* p = (const float4*)(probs + (size_t)hb * NPROB) + (size_t)hs * PER4;
        for (int i = tid; i < PER4; i += NTHREADS) {
            float4 v = p[i];
            if (v.x >= SCORE_THR) atomicAdd(&sm.lh[score_bin(__float_as_uint(v.x))], 1u);
            if (v.y >= SCORE_THR) atomicAdd(&sm.lh[score_bin(__float_as_uint(v.y))], 1u);
            if (v.z >= SCORE_THR) atomicAdd(&sm.lh[score_bin(__float_as_uint(v.z))], 1u);
            if (v.w >= SCORE_THR) atomicAdd(&sm.lh[score_bin(__float_as_uint(v.w))], 1u);
        }
    }
    __syncthreads();
    grid.sync();
    // merge local -> global (hist is zeroed everywhere now)
    for (int i = tid; i < NBINS; i += NTHREADS) {
        unsigned v = sm.lh[i];
        if (v) atomicAdd(&hist[hb * NBINS + i], v);
    }
    grid.sync();

    // ---- P2: select (blocks 0..7): suffix-scan pfx[B] = #{scores in bins >= B} ----
    if (bid < NB) {
        const int b = bid, t = tid;
        for (int i = t; i < NBINS; i += 256) sm.sel.h[i] = hist[b * NBINS + i];
        if (t == 0) sm.sel.sb = 0;
        __syncthreads();
        unsigned s = 0;
        #pragma unroll
        for (int i = 0; i < 8; ++i) s += sm.sel.h[t * 8 + i];
        sm.sel.csum[t] = s;
        __syncthreads();
        for (int off = 1; off < 256; off <<= 1) {
            unsigned v = (t + off < 256) ? sm.sel.csum[t + off] : 0u;
            __syncthreads();
            sm.sel.csum[t] += v;
            __syncthreads();
        }
        unsigned run = sm.sel.csum[t];
        #pragma unroll
        for (int i = 0; i < 8; ++i) { sm.sel.pfx[t * 8 + i] = run; run -= sm.sel.h[t * 8 + i]; }
        if (t == 0) sm.sel.pfx[NBINS] = 0;
        __syncthreads();
        #pragma unroll
        for (int i = 0; i < 8; ++i) {
            int B = t * 8 + i;
            if (sm.sel.pfx[B] >= TOPK && sm.sel.pfx[B + 1] < TOPK) sm.sel.sb = (unsigned)B;
        }
        __syncthreads();
        if (t == 0) {
            unsigned bs = sm.sel.sb;
            unsigned n = sm.sel.pfx[bs];
            meta[b].bstar = bs;
            meta[b].cnt = n < CAP ? n : CAP;
        }
        for (int i = t; i < NBINS; i += 256) {
            binpfx[b * (NBINS + 1) + i] = sm.sel.pfx[i];
            cursor[b * NBINS + i] = sm.sel.pfx[i + 1];    // bin segment start
        }
        if (t == 0) binpfx[b * (NBINS + 1) + NBINS] = 0;
    }
    grid.sync();

    // ---- P3: compact into bin-segmented cand[] via per-bin cursors ----
    {
        unsigned bstar = meta[hb].bstar;
        const float4* p = (const float4*)(probs + (size_t)hb * NPROB) + (size_t)hs * PER4;
        int base_elem = hs * PER4 * 4;
        unsigned long long* dst = cand + (size_t)hb * CAP;
        for (int i = tid; i < PER4; i += NTHREADS) {
            float4 v = p[i];
            int ei = base_elem + i * 4;
            float sv[4] = {v.x, v.y, v.z, v.w};
            #pragma unroll
            for (int c = 0; c < 4; ++c) {
                float s = sv[c];
                if (s >= SCORE_THR) {
                    unsigned fb = __float_as_uint(s);
                    unsigned B = score_bin(fb);
                    if (B >= bstar) {
                        unsigned pos = atomicAdd(&cursor[hb * NBINS + B], 1u);
                        if (pos < CAP) {
                            unsigned idx = (unsigned)(ei + c);
                            dst[pos] = ((unsigned long long)fb << 32) | (unsigned)(~idx);
                        }
                    }
                }
            }
        }
    }
    grid.sync();

    // ---- P4: rank within bin segment (~115 elems); write skey[rank], cellmap ----
    {
        int n = (int)meta[hb].cnt;
        if (hs < 16) {
            int nload = (n + 255) & ~255; if (nload > CAP) nload = CAP;
            for (int i = tid; i < nload; i += 256) sm.rk.k[i] = cand[(size_t)hb * CAP + i];
            for (int i = tid; i <= NBINS; i += 256) sm.rk.pfx[i] = binpfx[hb * (NBINS + 1) + i];
            __syncthreads();
            int p = hs * 256 + tid;
            if (p < n) {
                unsigned long long key = sm.rk.k[p];
                unsigned fb = (unsigned)(key >> 32);
                unsigned idx = ~(unsigned)key;
                unsigned B = score_bin(fb);
                int st = (int)sm.rk.pfx[B + 1];
                int en = (int)sm.rk.pfx[B]; if (en > n) en = n;
                int r = st;
                for (int i = st; i < en; ++i) r += (sm.rk.k[i] > key);
                if (r < TOPK) {
                    skey[(size_t)hb * TOPK + r] = key;
                    cellmap[(size_t)hb * NPROB + idx] = (unsigned short)r;
                }
            }
        }
    }
    grid.sync();

    // ---- P5: fix + out + cellmap cleanup (blocks 0..7, one batch each) ----
    if (bid < NB) {
        const int b = bid;
        int n = (int)meta[b].cnt;
        int nvalid = n < TOPK ? n : TOPK;
        unsigned short* cm = cellmap + (size_t)b * NPROB;

        constexpr int DYv[8] = {-1,-1,-1, 0, 0, 1, 1, 1};
        constexpr int DXv[8] = {-1, 0, 1,-1, 1,-1, 0, 1};
        unsigned long long l0[8], l1[8];
        int nc[8];
        unsigned myidx[8];

        #pragma unroll
        for (int q = 0; q < 8; ++q) {
            int r = q * 256 + tid;
            nc[q] = 0; l0[q] = 0; l1[q] = 0; myidx[q] = 0;
            unsigned char stinit = 2;
            if (r < nvalid) {
                unsigned long long key = skey[(size_t)b * TOPK + r];
                unsigned idx = ~(unsigned)key;
                myidx[q] = idx;
                int y = (int)(idx / W), x = (int)(idx % W);
                int c2 = 0;
                unsigned long long a0 = 0, a1 = 0;
                #pragma unroll
                for (int t8 = 0; t8 < 8; ++t8) {
                    int ny = y + DYv[t8], nx = x + DXv[t8];
                    if ((unsigned)ny < (unsigned)W && (unsigned)nx < (unsigned)W) {
                        unsigned rr = cm[ny * W + nx];
                        if (rr < (unsigned)r) {      // stale/poison (>=2048) auto-fails
                            if (c2 < 4) a0 |= (unsigned long long)rr << (c2 * 16);
                            else        a1 |= (unsigned long long)rr << ((c2 - 4) * 16);
                            c2++;
                        }
                    }
                }
                l0[q] = a0; l1[q] = a1; nc[q] = c2;
                stinit = (c2 == 0) ? 1 : 0;
            }
            if (r < TOPK) sm.fx.state[r] = stinit;
        }
        __syncthreads();

        // monotone fixpoint == sequential greedy NMS
        while (true) {
            if (tid == 0) sm.fx.changed = 0;
            __syncthreads();
            bool ch = false;
            #pragma unroll
            for (int q = 0; q < 8; ++q) {
                int r = q * 256 + tid;
                if (nc[q] > 0 && sm.fx.state[r] == 0) {
                    bool anyK = false, anyU = false;
                    int c = nc[q];
                    #pragma unroll
                    for (int l = 0; l < 8; ++l) {
                        if (l < c) {
                            unsigned rr = (l < 4)
                                ? (unsigned)((l0[q] >> (l * 16)) & 0xFFFFu)
                                : (unsigned)((l1[q] >> ((l - 4) * 16)) & 0xFFFFu);
                            unsigned char st = sm.fx.state[rr];
                            anyK |= (st == 1);
                            anyU |= (st == 0);
                        }
                    }
                    if (anyK)      { sm.fx.state[r] = 2; ch = true; }
                    else if (!anyU){ sm.fx.state[r] = 1; ch = true; }
                }
            }
            if (ch) sm.fx.changed = 1;
            __syncthreads();
            if (sm.fx.changed == 0) break;
            __syncthreads();
        }

        // refine + write + cleanup
        #pragma unroll
        for (int q = 0; q < 8; ++q) {
            int r = q * 256 + tid;
            float o0 = 0.f, o1 = 0.f, o2 = 0.f, o3 = 0.f, o4 = 0.f;
            bool valid = (r < nvalid);
            if (valid && sm.fx.state[r] == 1) {
                unsigned idx = myidx[q];
                unsigned long long key = skey[(size_t)b * TOPK + r];
                float sc = __uint_as_float((unsigned)(key >> 32));
                int y = (int)(idx / W), x = (int)(idx % W);
                const float4 d = ((const float4*)dev4)[(size_t)b * NPROB + idx];
                float b0 = (float)(4 * y + 2);
                float b1 = (float)(4 * x + 2);
                float b2 = (float)(4 * y + 24);
                float b3 = (float)(4 * x + 24);
                float r0 = b0 + d.x * 22.0f;
                float r1 = b1 + d.y * 22.0f;
                float r2 = b2 + d.z * 22.0f;
                float r3 = b3 + d.w * 22.0f;
                float rh = r2 - r0, rw = r3 - r1;
                float len = fmaxf(rh, rw);
                float c0 = r0 + rh * 0.5f, c1v = r1 + rw * 0.5f;
                float u0 = c0 - 0.5f * len, u1 = c1v - 0.5f * len;
                float v0 = u0 + len, v1 = u1 + len;
                o0 = fminf(fmaxf(u0, 1.0f), 3095.0f);
                o1 = fminf(fmaxf(u1, 1.0f), 3095.0f);
                o2 = fminf(fmaxf(v0, 1.0f), 3095.0f);
                o3 = fminf(fmaxf(v1, 1.0f), 3095.0f);
                o4 = sc;
            }
            float* op = out + ((size_t)b * TOPK + r) * 5;
            op[0] = o0; op[1] = o1; op[2] = o2; op[3] = o3; op[4] = o4;
            if (valid) cm[myidx[q]] = 0xFFFFu;   // reset touched cells for next replay
        }
    }
}

extern "C" void kernel_launch(void* const* d_in, const int* in_sizes, int n_in,
                              void* d_out, int out_size, void* d_ws, size_t ws_size,
                              hipStream_t stream) {
    (void)in_sizes; (void)n_in; (void)out_size;
    if (ws_size < (size_t)WS_TOTAL) return;

    const float* probs = (const float*)d_in[0];
    const float* devs  = (const float*)d_in[1];
    float* out = (float*)d_out;
    char* ws = (char*)d_ws;

    unsigned short* cellmap = (unsigned short*)(ws + MAP_OFF);
    unsigned* hist = (unsigned*)(ws + HIST_OFF);
    Meta* meta = (Meta*)(ws + META_OFF);
    unsigned* binpfx = (unsigned*)(ws + PFX_OFF);
    unsigned* cursor = (unsigned*)(ws + CUR_OFF);
    unsigned long long* cand = (unsigned long long*)(ws + CAND_OFF);
    unsigned long long* skey = (unsigned long long*)(ws + SKEY_OFF);

    void* args[] = { (void*)&probs, (void*)&devs, (void*)&out, (void*)&cellmap,
                     (void*)&hist, (void*)&meta, (void*)&binpfx, (void*)&cursor,
                     (void*)&cand, (void*)&skey };
    hipLaunchCooperativeKernel((const void*)fused_kernel,
                               dim3(NBLOCKS), dim3(NTHREADS), args, 0, stream);
}

// Round 8
// 75.249 us; speedup vs baseline: 3.0981x; 3.0981x over previous
//
#include <hip/hip_runtime.h>
#include <stdint.h>

#define W 768
#define NPROB (768*768)
#define NB 8
#define NBINS 2048           // 12-bit bins: (fb>>12)&0x7FF within the [0.5,1) binade
#define CAP 4096
#define TOPK 2048
#define SCORE_THR 0.6f
#define SUBS 32              // blocks per batch for hist/compact
#define PER4 (NPROB/4/SUBS)  // 4608 float4 per sub-block

// ws layout (bytes). cellmap needs NO init (validated round 7): stale/poison
// values (0xAAAA/0xFFFF) are >=2048 so `rank < r` auto-fails; cells written
// this call are reset in fixout's cleanup tail -> replays deterministic.
#define MAP_OFF    0
#define MAP_BYTES  (NB*NPROB*2)                 // 9,437,184
#define HPART_OFF  (MAP_OFF + MAP_BYTES)
#define HPART_BYTES (NB*SUBS*NBINS*4)           // 2,097,152
#define META_OFF   (HPART_OFF + HPART_BYTES)
#define PFX_OFF    (META_OFF + 256)
#define PFX_BYTES  (NB*(NBINS+1)*4)
#define CUR_OFF    (PFX_OFF + PFX_BYTES)
#define CUR_BYTES  (NB*NBINS*4)
#define CAND_OFF   (CUR_OFF + CUR_BYTES)
#define CAND_BYTES (NB*CAP*8)
#define SKEY_OFF   (CAND_OFF + CAND_BYTES)
#define SKEY_BYTES (NB*TOPK*8)
#define WS_TOTAL   (SKEY_OFF + SKEY_BYTES)

struct Meta { unsigned bstar; unsigned cnt; unsigned pad0; unsigned pad1; };

// valid scores are gated to [0.6,1.0) -> exponent 126 binade; bits monotone.
// 12-bit-granularity bin = top-11 mantissa bits (bit23 = exp LSB = 0).
__device__ __forceinline__ unsigned score_bin(unsigned fb) {
    return (fb >> 12) & 0x7FFu;
}

// Per-block private histogram partials: plain stores, no pre-zero, no atomics.
__global__ __launch_bounds__(256) void hist_kernel(const float* __restrict__ probs,
                                                   unsigned* __restrict__ hpart) {
    __shared__ unsigned lh[NBINS];
    int b = blockIdx.y, hs = blockIdx.x;
    for (int i = threadIdx.x; i < NBINS; i += 256) lh[i] = 0;
    __syncthreads();
    const float4* p = (const float4*)(probs + (size_t)b * NPROB) + (size_t)hs * PER4;
    for (int i = threadIdx.x; i < PER4; i += 256) {
        float4 v = p[i];
        if (v.x >= SCORE_THR) atomicAdd(&lh[score_bin(__float_as_uint(v.x))], 1u);
        if (v.y >= SCORE_THR) atomicAdd(&lh[score_bin(__float_as_uint(v.y))], 1u);
        if (v.z >= SCORE_THR) atomicAdd(&lh[score_bin(__float_as_uint(v.z))], 1u);
        if (v.w >= SCORE_THR) atomicAdd(&lh[score_bin(__float_as_uint(v.w))], 1u);
    }
    __syncthreads();
    unsigned* gh = hpart + ((size_t)(b * SUBS + hs)) * NBINS;
    for (int i = threadIdx.x; i < NBINS; i += 256) gh[i] = lh[i];
}

// Reduce partials, suffix-scan pfx[B] = #{scores in bins >= B}, find bstar,
// write binpfx + per-bin cursors (segment starts).
__global__ __launch_bounds__(256) void select_kernel(const unsigned* __restrict__ hpart,
                                                     Meta* __restrict__ meta,
                                                     unsigned* __restrict__ binpfx,
                                                     unsigned* __restrict__ cursor) {
    int b = blockIdx.x;
    __shared__ unsigned h[NBINS];
    __shared__ unsigned pfx[NBINS + 1];
    __shared__ unsigned csum[256];
    __shared__ unsigned sb;
    int t = threadIdx.x;
    for (int i = t; i < NBINS; i += 256) {
        unsigned s = 0;
        const unsigned* hp = hpart + (size_t)b * SUBS * NBINS + i;
        #pragma unroll 8
        for (int p = 0; p < SUBS; ++p) s += hp[(size_t)p * NBINS];
        h[i] = s;
    }
    if (t == 0) sb = 0;
    __syncthreads();
    unsigned s = 0;
    #pragma unroll
    for (int i = 0; i < 8; ++i) s += h[t * 8 + i];
    csum[t] = s;
    __syncthreads();
    for (int off = 1; off < 256; off <<= 1) {
        unsigned v = (t + off < 256) ? csum[t + off] : 0u;
        __syncthreads();
        csum[t] += v;
        __syncthreads();
    }
    unsigned run = csum[t];           // sum over bins >= 8t
    #pragma unroll
    for (int i = 0; i < 8; ++i) { pfx[t * 8 + i] = run; run -= h[t * 8 + i]; }
    if (t == 0) pfx[NBINS] = 0;
    __syncthreads();
    #pragma unroll
    for (int i = 0; i < 8; ++i) {
        int B = t * 8 + i;
        if (pfx[B] >= TOPK && pfx[B + 1] < TOPK) sb = (unsigned)B;  // unique writer
    }
    __syncthreads();
    if (t == 0) {
        unsigned bs = sb;
        unsigned n = pfx[bs];
        meta[b].bstar = bs;
        meta[b].cnt = n < CAP ? n : CAP;
    }
    for (int i = t; i < NBINS; i += 256) {
        binpfx[b * (NBINS + 1) + i] = pfx[i];
        cursor[b * NBINS + i] = pfx[i + 1];   // segment start for bin i
    }
    if (t == 0) binpfx[b * (NBINS + 1) + NBINS] = 0;
}

// Scatter candidates into bin-segmented cand[] via per-bin cursors.
__global__ __launch_bounds__(256) void compact_kernel(const float* __restrict__ probs,
                                                      const Meta* __restrict__ meta,
                                                      unsigned* __restrict__ cursor,
                                                      unsigned long long* __restrict__ cand) {
    int b = blockIdx.y;
    unsigned bstar = meta[b].bstar;
    int base_elem = blockIdx.x * PER4 * 4;
    const float4* p = (const float4*)(probs + (size_t)b * NPROB) + (size_t)blockIdx.x * PER4;
    unsigned long long* dst = cand + (size_t)b * CAP;
    for (int i = threadIdx.x; i < PER4; i += 256) {
        float4 v = p[i];
        int ei = base_elem + i * 4;
        float sv[4] = {v.x, v.y, v.z, v.w};
        #pragma unroll
        for (int c = 0; c < 4; ++c) {
            float s = sv[c];
            if (s >= SCORE_THR) {
                unsigned fb = __float_as_uint(s);
                unsigned B = score_bin(fb);
                if (B >= bstar) {
                    unsigned pos = atomicAdd(&cursor[b * NBINS + B], 1u);
                    if (pos < CAP) {
                        unsigned idx = (unsigned)(ei + c);
                        dst[pos] = ((unsigned long long)fb << 32) | (unsigned)(~idx);
                    }
                }
            }
        }
    }
}

// Exact ranking via 32-bit in-bin keys: within a bin, order of the 64-bit key
// (fb,~idx) == order of packed32 = fb[11:0]<<20 | (~idx)[19:0]. Scans only the
// candidate's bin segment (~190 elems, broadcast-friendly). Writes skey[rank]
// and cellmap[cell]=rank (race-free: cell indices unique).
__global__ __launch_bounds__(256) void rank_kernel(const unsigned long long* __restrict__ cand,
                                                   const Meta* __restrict__ meta,
                                                   const unsigned* __restrict__ binpfx,
                                                   unsigned long long* __restrict__ skey,
                                                   unsigned short* __restrict__ cellmap) {
    int b = blockIdx.y;
    __shared__ unsigned k32[CAP];             // 16 KB
    __shared__ unsigned s_pfx[NBINS + 1];     // 8.2 KB
    int n = (int)meta[b].cnt;                 // <= CAP
    int nload = (n + 255) & ~255;
    if (nload > CAP) nload = CAP;
    for (int i = threadIdx.x; i < nload; i += 256) {
        unsigned long long key = cand[(size_t)b * CAP + i];
        unsigned fb = (unsigned)(key >> 32);
        k32[i] = ((fb & 0xFFFu) << 20) | ((unsigned)key & 0xFFFFFu);  // (unsigned)key == ~idx
    }
    for (int i = threadIdx.x; i <= NBINS; i += 256) s_pfx[i] = binpfx[b * (NBINS + 1) + i];
    __syncthreads();
    int p = blockIdx.x * 256 + threadIdx.x;
    if (p < n) {
        unsigned long long key = cand[(size_t)b * CAP + p];
        unsigned fb = (unsigned)(key >> 32);
        unsigned idx = ~(unsigned)key;
        unsigned B = score_bin(fb);
        unsigned my = k32[p];
        int st = (int)s_pfx[B + 1];
        int en = (int)s_pfx[B]; if (en > n) en = n;
        int r = st;
        for (int i = st; i < en; ++i) r += (k32[i] > my);
        if (r < TOPK) {
            skey[(size_t)b * TOPK + r] = key;
            cellmap[(size_t)b * NPROB + idx] = (unsigned short)r;
        }
    }
}

// Fused: neighbor discovery (8 cellmap loads/box), 2KB-LDS monotone fixpoint
// (unique fixpoint == sequential greedy NMS), refine + write + cellmap cleanup.
__global__ __launch_bounds__(1024) void fixout_kernel(const float* __restrict__ dev4,
                                                      const unsigned long long* __restrict__ skey,
                                                      const Meta* __restrict__ meta,
                                                      unsigned short* __restrict__ cellmap,
                                                      float* __restrict__ out) {
    int b = blockIdx.x;
    __shared__ unsigned char s_state[TOPK];   // 0=und 1=kept 2=dead
    __shared__ int s_changed;
    int tid = threadIdx.x;
    int n = (int)meta[b].cnt;
    int nvalid = n < TOPK ? n : TOPK;
    unsigned short* cm = cellmap + (size_t)b * NPROB;

    constexpr int DYv[8] = {-1,-1,-1, 0, 0, 1, 1, 1};
    constexpr int DXv[8] = {-1, 0, 1,-1, 1,-1, 0, 1};
    unsigned long long mykey[2];
    unsigned myidx[2];
    unsigned long long l0[2] = {0,0}, l1[2] = {0,0};
    int nc[2] = {0,0};
    bool vld[2];

    #pragma unroll 2
    for (int q = 0; q < 2; ++q) {
        int r = tid + q * 1024;
        vld[q] = (r < nvalid);
        mykey[q] = 0; myidx[q] = 0;
        unsigned char stinit = 2;
        if (vld[q]) {
            unsigned long long key = skey[(size_t)b * TOPK + r];
            mykey[q] = key;
            unsigned idx = ~(unsigned)key;
            myidx[q] = idx;
            int y = (int)(idx / W), x = (int)(idx % W);
            int c2 = 0;
            unsigned long long a0 = 0, a1 = 0;
            #pragma unroll
            for (int t8 = 0; t8 < 8; ++t8) {
                int ny = y + DYv[t8], nx = x + DXv[t8];
                if ((unsigned)ny < (unsigned)W && (unsigned)nx < (unsigned)W) {
                    unsigned rr = cm[ny * W + nx];
                    if (rr < (unsigned)r) {      // stale/poison (>=2048) auto-fails
                        if (c2 < 4) a0 |= (unsigned long long)rr << (c2 * 16);
                        else        a1 |= (unsigned long long)rr << ((c2 - 4) * 16);
                        c2++;
                    }
                }
            }
            l0[q] = a0; l1[q] = a1; nc[q] = c2;
            stinit = (c2 == 0) ? 1 : 0;
        }
        s_state[r] = stinit;
    }
    __syncthreads();

    while (true) {
        if (tid == 0) s_changed = 0;
        __syncthreads();
        bool ch = false;
        #pragma unroll 2
        for (int q = 0; q < 2; ++q) {
            int r = tid + q * 1024;
            if (nc[q] > 0 && s_state[r] == 0) {
                bool anyK = false, anyU = false;
                int c = nc[q];
                #pragma unroll
                for (int l = 0; l < 8; ++l) {
                    if (l < c) {
                        unsigned rr = (l < 4)
                            ? (unsigned)((l0[q] >> (l * 16)) & 0xFFFFu)
                            : (unsigned)((l1[q] >> ((l - 4) * 16)) & 0xFFFFu);
                        unsigned char st = s_state[rr];
                        anyK |= (st == 1);
                        anyU |= (st == 0);
                    }
                }
                if (anyK)      { s_state[r] = 2; ch = true; }
                else if (!anyU){ s_state[r] = 1; ch = true; }
            }
        }
        if (ch) s_changed = 1;
        __syncthreads();
        if (s_changed == 0) break;
        __syncthreads();
    }

    // refine + write all TOPK rows + cleanup touched cells
    #pragma unroll 2
    for (int q = 0; q < 2; ++q) {
        int r = tid + q * 1024;
        float o0 = 0.f, o1 = 0.f, o2 = 0.f, o3 = 0.f, o4 = 0.f;
        if (vld[q] && s_state[r] == 1) {
            unsigned idx = myidx[q];
            float sc = __uint_as_float((unsigned)(mykey[q] >> 32));
            int y = (int)(idx / W), x = (int)(idx % W);
            const float4 d = ((const float4*)dev4)[(size_t)b * NPROB + idx];
            float b0 = (float)(4 * y + 2);
            float b1 = (float)(4 * x + 2);
            float b2 = (float)(4 * y + 24);
            float b3 = (float)(4 * x + 24);
            float r0 = b0 + d.x * 22.0f;
            float r1 = b1 + d.y * 22.0f;
            float r2 = b2 + d.z * 22.0f;
            float r3 = b3 + d.w * 22.0f;
            float rh = r2 - r0, rw = r3 - r1;
            float len = fmaxf(rh, rw);
            float c0 = r0 + rh * 0.5f, c1v = r1 + rw * 0.5f;
            float u0 = c0 - 0.5f * len, u1 = c1v - 0.5f * len;
            float v0 = u0 + len, v1 = u1 + len;
            o0 = fminf(fmaxf(u0, 1.0f), 3095.0f);
            o1 = fminf(fmaxf(u1, 1.0f), 3095.0f);
            o2 = fminf(fmaxf(v0, 1.0f), 3095.0f);
            o3 = fminf(fmaxf(v1, 1.0f), 3095.0f);
            o4 = sc;
        }
        float* op = out + ((size_t)b * TOPK + r) * 5;
        op[0] = o0; op[1] = o1; op[2] = o2; op[3] = o3; op[4] = o4;
        if (vld[q]) cm[myidx[q]] = 0xFFFFu;   // reset for next replay
    }
}

extern "C" void kernel_launch(void* const* d_in, const int* in_sizes, int n_in,
                              void* d_out, int out_size, void* d_ws, size_t ws_size,
                              hipStream_t stream) {
    (void)in_sizes; (void)n_in; (void)out_size;
    if (ws_size < (size_t)WS_TOTAL) return;

    const float* probs = (const float*)d_in[0];
    const float* devs  = (const float*)d_in[1];
    float* out = (float*)d_out;
    char* ws = (char*)d_ws;

    unsigned short* cellmap = (unsigned short*)(ws + MAP_OFF);
    unsigned* hpart = (unsigned*)(ws + HPART_OFF);
    Meta* meta = (Meta*)(ws + META_OFF);
    unsigned* binpfx = (unsigned*)(ws + PFX_OFF);
    unsigned* cursor = (unsigned*)(ws + CUR_OFF);
    unsigned long long* cand = (unsigned long long*)(ws + CAND_OFF);
    unsigned long long* skey = (unsigned long long*)(ws + SKEY_OFF);

    hist_kernel<<<dim3(SUBS, NB), 256, 0, stream>>>(probs, hpart);
    select_kernel<<<NB, 256, 0, stream>>>(hpart, meta, binpfx, cursor);
    compact_kernel<<<dim3(SUBS, NB), 256, 0, stream>>>(probs, meta, cursor, cand);
    rank_kernel<<<dim3(CAP / 256, NB), 256, 0, stream>>>(cand, meta, binpfx, skey, cellmap);
    fixout_kernel<<<NB, 1024, 0, stream>>>(devs, skey, meta, cellmap, out);
}